// Round 8
// baseline (185.706 us; speedup 1.0000x reference)
//
#include <hip/hip_runtime.h>
#include <hip/hip_bf16.h>
#include <math.h>

typedef short s8v __attribute__((ext_vector_type(8)));
typedef float f4v __attribute__((ext_vector_type(4)));

#define HH 256
#define TP 32              // points per block, two halves of 16
#define NTHREADS 256
// LDS strides in SHORTS. ks-chunk = 64 rows * 8 shorts + 8 pad = 520 (1040 B;
// 16 B rotation per ks spreads banks -> conflict-free b64 scatter writes)
#define KSTR 520
#define TSTR 4160          // 8 * KSTR: one A-tile (16 pts x 256 feats, frag-linear)
#define NTILES 6           // tile t = s*2 + h
#define PLANE (NTILES * TSTR)   // 24960 shorts = 49.9 KB

__device__ __forceinline__ unsigned short bf_rne(float x){
    union{float f;unsigned u;}v; v.f=x;
    unsigned r = v.u + 0x7FFFu + ((v.u >> 16) & 1u);
    return (unsigned short)(r >> 16);
}
__device__ __forceinline__ unsigned pack_rne2(float a, float b){
    union { __hip_bfloat162 h; unsigned u; } v;
    v.h = __float22bfloat162_rn(float2{a, b});
    return v.u;
}

// ---- prep: unchanged from R7 (verified) ----
__global__ __launch_bounds__(256)
void prep_weights(const float* __restrict__ W1, const float* __restrict__ W2,
                  const float* __restrict__ W3, const float* __restrict__ W0,
                  const float* __restrict__ b0, const float* __restrict__ W4,
                  unsigned short* __restrict__ wsB, float* __restrict__ wsF)
{
    int t = blockIdx.x * 256 + threadIdx.x;
    if (t < 24576) {
        int layer = t >> 13;
        int rem = t & 8191;
        int l  = rem & 63;
        int ks = (rem >> 6) & 7;
        int nt = rem >> 9;
        const float* W = (layer == 0) ? W1 : (layer == 1) ? W2 : W3;
        int n_out = nt * 16 + (l & 15);
        int quad  = l >> 4;
        const float* row = W + n_out * HH;
        s8v hi;
        #pragma unroll
        for (int j = 0; j < 8; ++j) {
            int n_in = quad * 64 + (j & 3) * 16 + ((j >> 2) << 3) + ks;
            hi[j] = (short)bf_rne(row[n_in]);
        }
        int dst = ((nt * 8 + ks) * 64 + l) * 8;
        *(s8v*)(wsB + layer * 65536 + dst) = hi;
    } else if (t < 24832) {
        int n = t - 24576;
        int pos = ((n & 7) * 4 + (n >> 6)) * 8 + ((n >> 4) & 3) + 4 * ((n >> 3) & 1);
        wsF[pos]       = W0[2 * n];
        wsF[256 + pos] = W0[2 * n + 1];
        wsF[512 + pos] = b0[n];
        wsF[768 + pos] = W4[n];
    }
}

// ---- main: half-split software pipeline, MFMA interleaved with transform ----
__global__ __launch_bounds__(NTHREADS, 2)
void capnn_mfma(const float* __restrict__ inp,
                const float* __restrict__ b1, const float* __restrict__ b2,
                const float* __restrict__ b3, const float* __restrict__ b4,
                const float* __restrict__ W4raw,
                const float* __restrict__ lgr, const float* __restrict__ lcc,
                const float* __restrict__ lil,
                const float* __restrict__ imean, const float* __restrict__ istd,
                const float* __restrict__ tmean, const float* __restrict__ tstd,
                const unsigned short* __restrict__ wsW,
                const float* __restrict__ wsF,
                float* __restrict__ out, int N)
{
    __shared__ __align__(16) unsigned short Ahi[PLANE];
    __shared__ float sn_sh[TP], tn_sh[TP];
    __shared__ float head_part[TP * 3 * 4];   // [(s*TP+p)*4 + w]

    const int tid  = threadIdx.x;
    const int lane = tid & 63;
    const int w    = tid >> 6;
    const int m16  = lane & 15;
    const int q    = lane >> 4;
    const int pbase = blockIdx.x * TP;

    const float* __restrict__ w00p = wsF;
    const float* __restrict__ w01p = wsF + 256;
    const float* __restrict__ b0p  = wsF + 512;

    // preload per-thread weights: head W4 and biases for layers 1..3
    float w4v[4], biasv[3][4];
    #pragma unroll
    for (int i = 0; i < 4; ++i) {
        const int n = w * 64 + i * 16 + m16;
        w4v[i] = W4raw[n];
        biasv[0][i] = b1[n];
        biasv[1][i] = b2[n];
        biasv[2][i] = b3[n];
    }

    if (tid < TP) {
        int pg = pbase + tid;
        float s = 0.f, t = 0.f;
        if (pg < N) { s = inp[2 * pg]; t = inp[2 * pg + 1]; }
        sn_sh[tid] = (s - imean[0]) / (istd[0] + 1e-8f);
        tn_sh[tid] = (t - imean[1]) / (istd[1] + 1e-8f);
    }
    __syncthreads();

    // ---- building blocks ----
    // layer-0 chunk: half h, k-group g2 (8 features, b128 writes per stream)
    auto l0_half = [&](int h, int g2) {
        const int l  = tid & 63;
        const int wv = tid >> 6;
        const int p16 = l & 15, quad = l >> 4;
        const int ks = wv + 4 * g2;
        const int pos = (ks * 4 + quad) * 8;
        float4 wA0 = *(const float4*)(w00p + pos);
        float4 wA1 = *(const float4*)(w00p + pos + 4);
        float4 wB0 = *(const float4*)(w01p + pos);
        float4 wB1 = *(const float4*)(w01p + pos + 4);
        float4 bb0 = *(const float4*)(b0p + pos);
        float4 bb1 = *(const float4*)(b0p + pos + 4);
        float w00v[8] = {wA0.x,wA0.y,wA0.z,wA0.w,wA1.x,wA1.y,wA1.z,wA1.w};
        float w01v[8] = {wB0.x,wB0.y,wB0.z,wB0.w,wB1.x,wB1.y,wB1.z,wB1.w};
        float b0v[8]  = {bb0.x,bb0.y,bb0.z,bb0.w,bb1.x,bb1.y,bb1.z,bb1.w};
        const float sn = sn_sh[h * 16 + p16], tn = tn_sh[h * 16 + p16];
        float av[8], d1v[8], d2v[8];
        #pragma unroll
        for (int j = 0; j < 8; ++j) {
            float z = fmaf(w00v[j], sn, fmaf(w01v[j], tn, b0v[j]));
            float e = __expf(2.f * z);
            float a = 1.f - 2.f * __builtin_amdgcn_rcpf(e + 1.f);
            float g = 1.f - a * a;
            float d1 = g * w01v[j];
            float d2 = -2.f * a * d1 * w01v[j];
            av[j] = a; d1v[j] = d1; d2v[j] = d2;
        }
        const int base = ks * KSTR + l * 8;
        #pragma unroll
        for (int s = 0; s < 3; ++s) {
            const float* V = (s == 0) ? av : (s == 1) ? d1v : d2v;
            int4 hi4;
            hi4.x = (int)pack_rne2(V[0], V[1]);
            hi4.y = (int)pack_rne2(V[2], V[3]);
            hi4.z = (int)pack_rne2(V[4], V[5]);
            hi4.w = (int)pack_rne2(V[6], V[7]);
            *(int4*)&Ahi[(s * 2 + h) * TSTR + base] = hi4;
        }
    };

    // one K step: half h, k-slice ks, layer weights Wl -> 12 MFMAs
    auto kstep = [&](int h, f4v (&acc)[3][4], const unsigned short* __restrict__ Wl, int ks) {
        s8v a[3];
        const int aoff = ks * KSTR + lane * 8;
        #pragma unroll
        for (int s = 0; s < 3; ++s)
            a[s] = *(const s8v*)&Ahi[(s * 2 + h) * TSTR + aoff];
        #pragma unroll
        for (int i = 0; i < 4; ++i) {
            const int off = (((w * 4 + i) * 8 + ks) * 64 + lane) * 8;
            s8v bh = *(const s8v*)(Wl + off);
            #pragma unroll
            for (int s = 0; s < 3; ++s)
                acc[s][i] = __builtin_amdgcn_mfma_f32_16x16x32_bf16(a[s], bh, acc[s][i], 0, 0, 0);
        }
    };

    auto initacc = [&](f4v (&acc)[3][4], int L) {
        #pragma unroll
        for (int i = 0; i < 4; ++i) {
            float b = biasv[L][i];
            acc[0][i] = (f4v){b, b, b, b};
            acc[1][i] = (f4v){0.f, 0.f, 0.f, 0.f};
            acc[2][i] = (f4v){0.f, 0.f, 0.f, 0.f};
        }
    };

    // transform chunk r of half h: 4 tanh-triples + 3 b64 LDS writes
    auto tchunk = [&](int h, int r, const f4v (&acc)[3][4]) {
        const int ksw  = m16 & 7;
        const int hsel = m16 >> 3;
        const int wbase = ksw * KSTR + (16 * w + q * 4) * 8 + 4 * hsel;
        float Av[3][4];
        #pragma unroll
        for (int i = 0; i < 4; ++i) {
            float z  = acc[0][i][r];
            float z1 = acc[1][i][r];
            float z2 = acc[2][i][r];
            float e = __expf(2.f * z);
            float a = 1.f - 2.f * __builtin_amdgcn_rcpf(e + 1.f);
            float g = 1.f - a * a;
            float d1 = g * z1;
            float d2 = fmaf(g, z2, -2.f * a * d1 * z1);
            Av[0][i] = a; Av[1][i] = d1; Av[2][i] = d2;
        }
        #pragma unroll
        for (int s = 0; s < 3; ++s) {
            int2 hi2;
            hi2.x = (int)pack_rne2(Av[s][0], Av[s][1]);
            hi2.y = (int)pack_rne2(Av[s][2], Av[s][3]);
            *(int2*)&Ahi[(s * 2 + h) * TSTR + wbase + r * 8] = hi2;
        }
    };

    // head chunk r of half h: transform + dot with W4 into hp[s][r]
    auto headchunk = [&](int r, const f4v (&acc)[3][4], float (&hp)[3][4]) {
        #pragma unroll
        for (int i = 0; i < 4; ++i) {
            float z  = acc[0][i][r];
            float z1 = acc[1][i][r];
            float z2 = acc[2][i][r];
            float e = __expf(2.f * z);
            float a = 1.f - 2.f * __builtin_amdgcn_rcpf(e + 1.f);
            float g = 1.f - a * a;
            float d1 = g * z1;
            float d2 = fmaf(g, z2, -2.f * a * d1 * z1);
            hp[0][r] = fmaf(w4v[i], a,  hp[0][r]);
            hp[1][r] = fmaf(w4v[i], d1, hp[1][r]);
            hp[2][r] = fmaf(w4v[i], d2, hp[2][r]);
        }
    };

    auto headflush = [&](int h, float (&hp)[3][4]) {
        #pragma unroll
        for (int m = 1; m < 16; m <<= 1)
            #pragma unroll
            for (int s = 0; s < 3; ++s)
                #pragma unroll
                for (int r = 0; r < 4; ++r)
                    hp[s][r] += __shfl_xor(hp[s][r], m);
        if (m16 == 0) {
            #pragma unroll
            for (int s = 0; s < 3; ++s)
                #pragma unroll
                for (int r = 0; r < 4; ++r)
                    head_part[(s * TP + h * 16 + q * 4 + r) * 4 + w] = hp[s][r];
        }
    };

    const unsigned short* __restrict__ W1p = wsW;
    const unsigned short* __restrict__ W2p = wsW + 65536;
    const unsigned short* __restrict__ W3p = wsW + 131072;

    f4v accA[3][4], accB[3][4];

    // ---- prologue: layer 0 for h0 ----
    l0_half(0, 0);
    l0_half(0, 1);
    __syncthreads();

    // ---- region 1: K(h0,L1) || layer0(h1) ----
    initacc(accA, 0);
    #pragma unroll
    for (int ks = 0; ks < 8; ++ks) {
        kstep(0, accA, W1p, ks);
        if (ks == 1) l0_half(1, 0);
        if (ks == 4) l0_half(1, 1);
    }
    __syncthreads();

    // ---- region 2: K(h1,L1) || T(h0,L1) ----
    initacc(accB, 0);
    #pragma unroll
    for (int ks = 0; ks < 8; ++ks) {
        kstep(1, accB, W1p, ks);
        if (ks & 1) tchunk(0, ks >> 1, accA);
    }
    __syncthreads();

    // ---- region 3: K(h0,L2) || T(h1,L1) ----
    initacc(accA, 1);
    #pragma unroll
    for (int ks = 0; ks < 8; ++ks) {
        kstep(0, accA, W2p, ks);
        if (ks & 1) tchunk(1, ks >> 1, accB);
    }
    __syncthreads();

    // ---- region 4: K(h1,L2) || T(h0,L2) ----
    initacc(accB, 1);
    #pragma unroll
    for (int ks = 0; ks < 8; ++ks) {
        kstep(1, accB, W2p, ks);
        if (ks & 1) tchunk(0, ks >> 1, accA);
    }
    __syncthreads();

    // ---- region 5: K(h0,L3) || T(h1,L2) ----
    initacc(accA, 2);
    #pragma unroll
    for (int ks = 0; ks < 8; ++ks) {
        kstep(0, accA, W3p, ks);
        if (ks & 1) tchunk(1, ks >> 1, accB);
    }
    __syncthreads();

    // ---- region 6: K(h1,L3) || HEAD(h0) ----
    initacc(accB, 2);
    float hp0[3][4];
    #pragma unroll
    for (int s = 0; s < 3; ++s)
        #pragma unroll
        for (int r = 0; r < 4; ++r) hp0[s][r] = 0.f;
    #pragma unroll
    for (int ks = 0; ks < 8; ++ks) {
        kstep(1, accB, W3p, ks);
        if (ks & 1) headchunk(ks >> 1, accA, hp0);
    }
    headflush(0, hp0);

    // ---- HEAD(h1), bare ----
    float hp1[3][4];
    #pragma unroll
    for (int s = 0; s < 3; ++s)
        #pragma unroll
        for (int r = 0; r < 4; ++r) hp1[s][r] = 0.f;
    #pragma unroll
    for (int r = 0; r < 4; ++r) headchunk(r, accB, hp1);
    headflush(1, hp1);
    __syncthreads();

    // ---- Verhulst residuals + store ----
    if (tid < TP) {
        float sv = 0.f, s1v = 0.f, s2v = 0.f;
        #pragma unroll
        for (int ww = 0; ww < 4; ++ww) {
            sv  += head_part[(0 * TP + tid) * 4 + ww];
            s1v += head_part[(1 * TP + tid) * 4 + ww];
            s2v += head_part[(2 * TP + tid) * 4 + ww];
        }
        int pg = pbase + tid;
        if (pg < N) {
            float r_  = expf(-lgr[0]);
            float Kc  = 0.2f + 0.8f / (1.f + expf(-lcc[0]));
            float Cc  = 0.1f / (1.f + expf(-lil[0]));
            float kci = 1.f / (Kc - Cc);
            float ts = tstd[0], tm = tmean[0];
            float U   = (sv + b4[0]) * ts + tm;
            float Ut  = s1v * ts;
            float Utt = s2v * ts;
            float Um  = U - Cc;
            float G   = r_ * Um * (1.f - Um * kci);
            float Gt  = r_ * Ut * (1.f - 2.f * Um * kci);
            out[pg]         = U;
            out[N + pg]     = Ut - G;
            out[2 * N + pg] = Utt - Gt;
        }
    }
}

extern "C" void kernel_launch(void* const* d_in, const int* in_sizes, int n_in,
                              void* d_out, int out_size, void* d_ws, size_t ws_size,
                              hipStream_t stream) {
    const float* inp   = (const float*)d_in[0];
    const float* W0    = (const float*)d_in[1];
    const float* b0    = (const float*)d_in[2];
    const float* W1    = (const float*)d_in[3];
    const float* b1    = (const float*)d_in[4];
    const float* W2    = (const float*)d_in[5];
    const float* b2    = (const float*)d_in[6];
    const float* W3    = (const float*)d_in[7];
    const float* b3    = (const float*)d_in[8];
    const float* W4    = (const float*)d_in[9];
    const float* b4    = (const float*)d_in[10];
    const float* lgr   = (const float*)d_in[11];
    const float* lcc   = (const float*)d_in[12];
    const float* lil   = (const float*)d_in[13];
    const float* imean = (const float*)d_in[14];
    const float* istd  = (const float*)d_in[15];
    const float* tmean = (const float*)d_in[16];
    const float* tstd  = (const float*)d_in[17];

    unsigned short* wsB = (unsigned short*)d_ws;            // 384 KB B-frags (RNE bf16)
    float* wsF = (float*)((char*)d_ws + 393216);            // 4 KB pi-planes

    const int N = in_sizes[0] / 2;
    const int gridMain = (N + TP - 1) / TP;                 // 2048 blocks

    hipLaunchKernelGGL(prep_weights, dim3(97), dim3(256), 0, stream,
                       W1, W2, W3, W0, b0, W4, wsB, wsF);
    hipLaunchKernelGGL(capnn_mfma, dim3(gridMain), dim3(NTHREADS), 0, stream,
                       inp, b1, b2, b3, b4, W4,
                       lgr, lcc, lil, imean, istd, tmean, tstd,
                       wsB, wsF, (float*)d_out, N);
}

// Round 9
// 182.996 us; speedup vs baseline: 1.0148x; 1.0148x over previous
//
#include <hip/hip_runtime.h>
#include <hip/hip_bf16.h>
#include <math.h>

typedef short s8v __attribute__((ext_vector_type(8)));
typedef float f4v __attribute__((ext_vector_type(4)));

#define HH 256
#define TP 16              // points per block
#define NTHREADS 256
// LDS strides in SHORTS. ks-chunk = 64 rows * 8 shorts + 8 pad = 520 (1040 B;
// 16 B rotation per ks spreads banks -> conflict-free b64 scatter writes)
#define KSTR 520
#define TSTR 4160          // 8 * KSTR: one A-tile (16 pts x 256 feats, frag-linear)
#define NTILES 3           // one tile per stream
#define PLANE (NTILES * TSTR)   // 12480 shorts = 24.96 KB

__device__ __forceinline__ unsigned short bf_rne(float x){
    union{float f;unsigned u;}v; v.f=x;
    unsigned r = v.u + 0x7FFFu + ((v.u >> 16) & 1u);
    return (unsigned short)(r >> 16);
}
__device__ __forceinline__ unsigned pack_rne2(float a, float b){
    union { __hip_bfloat162 h; unsigned u; } v;
    v.h = __float22bfloat162_rn(float2{a, b});
    return v.u;
}

// ---- prep: B-fragments (RNE bf16) with k-permutation pi folded in, plus
// pi-ordered fp32 planes for W0 cols, b0, W4.  (verified R4-R8)
// pi(n): ks=n&7, quad=n>>6, j=((n>>4)&3)+4*((n>>3)&1); pi^-1(ks,quad,j) =
// quad*64 + (j&3)*16 + (j>>2)*8 + ks.
__global__ __launch_bounds__(256)
void prep_weights(const float* __restrict__ W1, const float* __restrict__ W2,
                  const float* __restrict__ W3, const float* __restrict__ W0,
                  const float* __restrict__ b0, const float* __restrict__ W4,
                  unsigned short* __restrict__ wsB, float* __restrict__ wsF)
{
    int t = blockIdx.x * 256 + threadIdx.x;
    if (t < 24576) {
        int layer = t >> 13;
        int rem = t & 8191;
        int l  = rem & 63;
        int ks = (rem >> 6) & 7;
        int nt = rem >> 9;
        const float* W = (layer == 0) ? W1 : (layer == 1) ? W2 : W3;
        int n_out = nt * 16 + (l & 15);
        int quad  = l >> 4;
        const float* row = W + n_out * HH;
        s8v hi;
        #pragma unroll
        for (int j = 0; j < 8; ++j) {
            int n_in = quad * 64 + (j & 3) * 16 + ((j >> 2) << 3) + ks;
            hi[j] = (short)bf_rne(row[n_in]);
        }
        int dst = ((nt * 8 + ks) * 64 + l) * 8;
        *(s8v*)(wsB + layer * 65536 + dst) = hi;
    } else if (t < 24832) {
        int n = t - 24576;
        int pos = ((n & 7) * 4 + (n >> 6)) * 8 + ((n >> 4) & 3) + 4 * ((n >> 3) & 1);
        wsF[pos]       = W0[2 * n];
        wsF[256 + pos] = W0[2 * n + 1];
        wsF[512 + pos] = b0[n];
        wsF[768 + pos] = W4[n];
    }
}

// ---- main: TP=16, single bf16 plane, small blocks for phase-mixing ----
__global__ __launch_bounds__(NTHREADS, 4)
void capnn_mfma(const float* __restrict__ inp,
                const float* __restrict__ b1, const float* __restrict__ b2,
                const float* __restrict__ b3, const float* __restrict__ b4,
                const float* __restrict__ W4raw,
                const float* __restrict__ lgr, const float* __restrict__ lcc,
                const float* __restrict__ lil,
                const float* __restrict__ imean, const float* __restrict__ istd,
                const float* __restrict__ tmean, const float* __restrict__ tstd,
                const unsigned short* __restrict__ wsW,
                const float* __restrict__ wsF,
                float* __restrict__ out, int N)
{
    __shared__ __align__(16) unsigned short Ahi[PLANE];
    __shared__ float sn_sh[TP], tn_sh[TP];
    __shared__ float head_part[TP * 3 * 4];   // [(s*TP+p)*4 + w]

    const int tid  = threadIdx.x;
    const int lane = tid & 63;
    const int w    = tid >> 6;
    const int m16  = lane & 15;
    const int q    = lane >> 4;
    const int pbase = blockIdx.x * TP;

    const float* __restrict__ w00p = wsF;
    const float* __restrict__ w01p = wsF + 256;
    const float* __restrict__ b0p  = wsF + 512;

    // preload per-thread weights: head W4 and biases for layers 1..3
    float w4v[4], biasv[3][4];
    #pragma unroll
    for (int i = 0; i < 4; ++i) {
        const int n = w * 64 + i * 16 + m16;
        w4v[i] = W4raw[n];
        biasv[0][i] = b1[n];
        biasv[1][i] = b2[n];
        biasv[2][i] = b3[n];
    }

    if (tid < TP) {
        int pg = pbase + tid;
        float s = 0.f, t = 0.f;
        if (pg < N) { s = inp[2 * pg]; t = inp[2 * pg + 1]; }
        sn_sh[tid] = (s - imean[0]) / (istd[0] + 1e-8f);
        tn_sh[tid] = (t - imean[1]) / (istd[1] + 1e-8f);
    }
    __syncthreads();

    // ---- layer 0: thread <-> (ks = wv+4g, row l); writes wave-contiguous b128
    {
        const int l  = tid & 63;
        const int wv = tid >> 6;
        const int p16 = l & 15, quad = l >> 4;
        const float sn = sn_sh[p16], tn = tn_sh[p16];
        #pragma unroll
        for (int g2 = 0; g2 < 2; ++g2) {
            const int ks = wv + 4 * g2;
            const int pos = (ks * 4 + quad) * 8;
            float4 wA0 = *(const float4*)(w00p + pos);
            float4 wA1 = *(const float4*)(w00p + pos + 4);
            float4 wB0 = *(const float4*)(w01p + pos);
            float4 wB1 = *(const float4*)(w01p + pos + 4);
            float4 bb0 = *(const float4*)(b0p + pos);
            float4 bb1 = *(const float4*)(b0p + pos + 4);
            float w00v[8] = {wA0.x,wA0.y,wA0.z,wA0.w,wA1.x,wA1.y,wA1.z,wA1.w};
            float w01v[8] = {wB0.x,wB0.y,wB0.z,wB0.w,wB1.x,wB1.y,wB1.z,wB1.w};
            float b0v[8]  = {bb0.x,bb0.y,bb0.z,bb0.w,bb1.x,bb1.y,bb1.z,bb1.w};
            float av[8], d1v[8], d2v[8];
            #pragma unroll
            for (int j = 0; j < 8; ++j) {
                float z = fmaf(w00v[j], sn, fmaf(w01v[j], tn, b0v[j]));
                float e = __expf(2.f * z);
                float a = 1.f - 2.f * __builtin_amdgcn_rcpf(e + 1.f);
                float g = 1.f - a * a;
                float d1 = g * w01v[j];
                float d2 = -2.f * a * d1 * w01v[j];
                av[j] = a; d1v[j] = d1; d2v[j] = d2;
            }
            const int base = ks * KSTR + l * 8;
            #pragma unroll
            for (int s = 0; s < 3; ++s) {
                const float* V = (s == 0) ? av : (s == 1) ? d1v : d2v;
                int4 hi4;
                hi4.x = (int)pack_rne2(V[0], V[1]);
                hi4.y = (int)pack_rne2(V[2], V[3]);
                hi4.z = (int)pack_rne2(V[4], V[5]);
                hi4.w = (int)pack_rne2(V[6], V[7]);
                *(int4*)&Ahi[s * TSTR + base] = hi4;
            }
        }
    }
    __syncthreads();

    // ---- layers 1..3: 12 MFMAs/ks ----
    for (int L = 0; L < 3; ++L) {
        const unsigned short* __restrict__ Wl = wsW + L * 65536;

        f4v acc[3][4];
        #pragma unroll
        for (int i = 0; i < 4; ++i) {
            float b = biasv[L][i];
            acc[0][i] = (f4v){b, b, b, b};
            acc[1][i] = (f4v){0.f, 0.f, 0.f, 0.f};
            acc[2][i] = (f4v){0.f, 0.f, 0.f, 0.f};
        }

        #pragma unroll
        for (int ks = 0; ks < 8; ++ks) {
            s8v a[3];
            const int aoff = ks * KSTR + lane * 8;
            #pragma unroll
            for (int s = 0; s < 3; ++s)
                a[s] = *(const s8v*)&Ahi[s * TSTR + aoff];
            #pragma unroll
            for (int i = 0; i < 4; ++i) {
                const int off = (((w * 4 + i) * 8 + ks) * 64 + lane) * 8;
                s8v bh = *(const s8v*)(Wl + off);
                #pragma unroll
                for (int s = 0; s < 3; ++s)
                    acc[s][i] = __builtin_amdgcn_mfma_f32_16x16x32_bf16(a[s], bh, acc[s][i], 0, 0, 0);
            }
        }

        if (L < 2) {
            __syncthreads();   // all waves done reading A before overwrite
            // ---- transform + pi-scatter: per (r,s) one b64 (4 consecutive j)
            const int ksw  = m16 & 7;
            const int hsel = m16 >> 3;
            const int wbase = ksw * KSTR + (16 * w + q * 4) * 8 + 4 * hsel;
            #pragma unroll
            for (int r = 0; r < 4; ++r) {
                float Av[3][4];
                #pragma unroll
                for (int i = 0; i < 4; ++i) {
                    float z  = acc[0][i][r];
                    float z1 = acc[1][i][r];
                    float z2 = acc[2][i][r];
                    float e = __expf(2.f * z);
                    float a = 1.f - 2.f * __builtin_amdgcn_rcpf(e + 1.f);
                    float g = 1.f - a * a;
                    float d1 = g * z1;
                    float d2 = fmaf(g, z2, -2.f * a * d1 * z1);
                    Av[0][i] = a; Av[1][i] = d1; Av[2][i] = d2;
                }
                #pragma unroll
                for (int s = 0; s < 3; ++s) {
                    int2 hi2;
                    hi2.x = (int)pack_rne2(Av[s][0], Av[s][1]);
                    hi2.y = (int)pack_rne2(Av[s][2], Av[s][3]);
                    *(int2*)&Ahi[s * TSTR + wbase + r * 8] = hi2;
                }
            }
            __syncthreads();
        } else {
            // ---- fused head: transform in regs, dot with W4 (fp32), reduce ----
            float hp[3][4];
            #pragma unroll
            for (int s = 0; s < 3; ++s)
                #pragma unroll
                for (int r = 0; r < 4; ++r) hp[s][r] = 0.f;
            #pragma unroll
            for (int r = 0; r < 4; ++r) {
                #pragma unroll
                for (int i = 0; i < 4; ++i) {
                    float z  = acc[0][i][r];
                    float z1 = acc[1][i][r];
                    float z2 = acc[2][i][r];
                    float e = __expf(2.f * z);
                    float a = 1.f - 2.f * __builtin_amdgcn_rcpf(e + 1.f);
                    float g = 1.f - a * a;
                    float d1 = g * z1;
                    float d2 = fmaf(g, z2, -2.f * a * d1 * z1);
                    hp[0][r] = fmaf(w4v[i], a,  hp[0][r]);
                    hp[1][r] = fmaf(w4v[i], d1, hp[1][r]);
                    hp[2][r] = fmaf(w4v[i], d2, hp[2][r]);
                }
            }
            // reduce across the 16-lane m16 group
            #pragma unroll
            for (int m = 1; m < 16; m <<= 1) {
                #pragma unroll
                for (int s = 0; s < 3; ++s)
                    #pragma unroll
                    for (int r = 0; r < 4; ++r)
                        hp[s][r] += __shfl_xor(hp[s][r], m);
            }
            if (m16 == 0) {
                #pragma unroll
                for (int s = 0; s < 3; ++s)
                    #pragma unroll
                    for (int r = 0; r < 4; ++r)
                        head_part[(s * TP + q * 4 + r) * 4 + w] = hp[s][r];
            }
            __syncthreads();
        }
    }

    // ---- Verhulst residuals + store ----
    if (tid < TP) {
        float sv = 0.f, s1v = 0.f, s2v = 0.f;
        #pragma unroll
        for (int ww = 0; ww < 4; ++ww) {
            sv  += head_part[(0 * TP + tid) * 4 + ww];
            s1v += head_part[(1 * TP + tid) * 4 + ww];
            s2v += head_part[(2 * TP + tid) * 4 + ww];
        }
        int pg = pbase + tid;
        if (pg < N) {
            float r_  = expf(-lgr[0]);
            float Kc  = 0.2f + 0.8f / (1.f + expf(-lcc[0]));
            float Cc  = 0.1f / (1.f + expf(-lil[0]));
            float kci = 1.f / (Kc - Cc);
            float ts = tstd[0], tm = tmean[0];
            float U   = (sv + b4[0]) * ts + tm;
            float Ut  = s1v * ts;
            float Utt = s2v * ts;
            float Um  = U - Cc;
            float G   = r_ * Um * (1.f - Um * kci);
            float Gt  = r_ * Ut * (1.f - 2.f * Um * kci);
            out[pg]         = U;
            out[N + pg]     = Ut - G;
            out[2 * N + pg] = Utt - Gt;
        }
    }
}

extern "C" void kernel_launch(void* const* d_in, const int* in_sizes, int n_in,
                              void* d_out, int out_size, void* d_ws, size_t ws_size,
                              hipStream_t stream) {
    const float* inp   = (const float*)d_in[0];
    const float* W0    = (const float*)d_in[1];
    const float* b0    = (const float*)d_in[2];
    const float* W1    = (const float*)d_in[3];
    const float* b1    = (const float*)d_in[4];
    const float* W2    = (const float*)d_in[5];
    const float* b2    = (const float*)d_in[6];
    const float* W3    = (const float*)d_in[7];
    const float* b3    = (const float*)d_in[8];
    const float* W4    = (const float*)d_in[9];
    const float* b4    = (const float*)d_in[10];
    const float* lgr   = (const float*)d_in[11];
    const float* lcc   = (const float*)d_in[12];
    const float* lil   = (const float*)d_in[13];
    const float* imean = (const float*)d_in[14];
    const float* istd  = (const float*)d_in[15];
    const float* tmean = (const float*)d_in[16];
    const float* tstd  = (const float*)d_in[17];

    unsigned short* wsB = (unsigned short*)d_ws;            // 384 KB B-frags (RNE bf16)
    float* wsF = (float*)((char*)d_ws + 393216);            // 4 KB pi-planes

    const int N = in_sizes[0] / 2;
    const int gridMain = (N + TP - 1) / TP;                 // 4096 blocks

    hipLaunchKernelGGL(prep_weights, dim3(97), dim3(256), 0, stream,
                       W1, W2, W3, W0, b0, W4, wsB, wsF);
    hipLaunchKernelGGL(capnn_mfma, dim3(gridMain), dim3(NTHREADS), 0, stream,
                       inp, b1, b2, b3, b4, W4,
                       lgr, lcc, lil, imean, istd, tmean, tstd,
                       wsB, wsF, (float*)d_out, N);
}